// Round 19
// baseline (189.472 us; speedup 1.0000x reference)
//
#include <hip/hip_runtime.h>
#include <hip/hip_bf16.h>
#include <math.h>

#define H_ 32
#define R_ 512
#define NOPE_ 128
#define ROPE_ 64
#define V_ 128
#define HID_ 4096
#define B_ 64
#define S_ 4096
#define TOPK_ 2048
#define DQ_ 192      // NOPE+ROPE
#define NQ_ 6144     // H*DQ
#define DKV_ 576     // R+ROPE
#define KCH_ 16      // K-chunks for Wq skinny GEMM
#define KCHO_ 8      // K-chunks for Wo skinny GEMM (round-19: halve op2 traffic)
#define ACH_ 8       // attention k-chunks
#define CHUNK_ 256   // TOPK/ACH
#define TILE_ 16     // gathered rows per inner iteration
#define NG_ (CHUNK_/TILE_)   // 16 inner iterations
#define DGSTR_ 264   // krows dgrp stride in shorts (16key*16d = 256 + 8 pad)
#define KRSZ_ (36*DGSTR_)    // shorts per buffer
#define VTS_ 24      // P_lds stride (shorts)

typedef __attribute__((ext_vector_type(8))) short bf16x8;
typedef __attribute__((ext_vector_type(4))) short s16x4;
typedef __attribute__((ext_vector_type(4))) float f32x4;
typedef __attribute__((ext_vector_type(16))) float f32x16;

__device__ __forceinline__ float4 ld4(const float* p) { return *reinterpret_cast<const float4*>(p); }
__device__ __forceinline__ short f2b(float f) {
  __hip_bfloat16 h = __float2bfloat16(f);
  short s; __builtin_memcpy(&s, &h, 2); return s;
}
__device__ __forceinline__ float b2f(short s) {
  union { unsigned u; float f; } x; x.u = ((unsigned)(unsigned short)s) << 16; return x.f;
}
__device__ __forceinline__ void split2(float v, short& h, short& l) {
  short hh = f2b(v);
  h = hh; l = f2b(v - b2f(hh));
}
__device__ __forceinline__ s16x4 tr_read(unsigned byte_addr) {
  s16x4 r;
  asm volatile("ds_read_b64_tr_b16 %0, %1" : "=v"(r) : "v"(byte_addr));
  return r;
}

// ---------------- skinny partial GEMM via MFMA bf16x3 (f32-class precision) ----------------
__global__ __launch_bounds__(256) void gemm64_mfma(const float* __restrict__ A,
    const float* __restrict__ A2,
    const float* __restrict__ Bm, float* __restrict__ Cp, int N, int K) {
  __shared__ __align__(16) short Ah[64*40], Al[64*40];   // [m][k32] stride 40
  __shared__ __align__(16) short Bh[128*40], Bl[128*40]; // [n][k32] stride 40
  const int t = threadIdx.x;
  const int nt = blockIdx.x, kc = blockIdx.y;
  const int n0 = nt*128;
  const int kchunk = K / gridDim.y, kbeg = kc*kchunk;
  const int lane = t & 63, wid = t >> 6;
  const int lk = lane & 15, lg = lane >> 4;
  const int wm2 = wid >> 1, wn2 = wid & 1;   // m-half(32), n-half(64)
  const int kq = t & 7, ng = t >> 3;         // B-transpose ownership
  f32x4 acc[2][4];
  #pragma unroll
  for (int mi=0;mi<2;mi++)
    #pragma unroll
    for (int nj=0;nj<4;nj++) acc[mi][nj] = (f32x4){0.f,0.f,0.f,0.f};

  for (int k0 = kbeg; k0 < kbeg + kchunk; k0 += 32) {
    #pragma unroll
    for (int l=0;l<2;l++) {
      int idx = t + l*256;
      int m = idx >> 3, kq2 = idx & 7;
      float4 v = ld4(&A[(size_t)m*K + k0 + kq2*4]);
      if (A2) {
        float4 w = ld4(&A2[(size_t)m*K + k0 + kq2*4]);
        v.x+=w.x; v.y+=w.y; v.z+=w.z; v.w+=w.w;
      }
      short4 h4, l4;
      split2(v.x, h4.x, l4.x); split2(v.y, h4.y, l4.y);
      split2(v.z, h4.z, l4.z); split2(v.w, h4.w, l4.w);
      *reinterpret_cast<short4*>(&Ah[m*40 + kq2*4]) = h4;
      *reinterpret_cast<short4*>(&Al[m*40 + kq2*4]) = l4;
    }
    {
      float4 v0 = ld4(&Bm[(size_t)(k0+kq*4+0)*N + n0 + ng*4]);
      float4 v1 = ld4(&Bm[(size_t)(k0+kq*4+1)*N + n0 + ng*4]);
      float4 v2 = ld4(&Bm[(size_t)(k0+kq*4+2)*N + n0 + ng*4]);
      float4 v3 = ld4(&Bm[(size_t)(k0+kq*4+3)*N + n0 + ng*4]);
      short4 hj, lj;
      split2(v0.x,hj.x,lj.x); split2(v1.x,hj.y,lj.y); split2(v2.x,hj.z,lj.z); split2(v3.x,hj.w,lj.w);
      *reinterpret_cast<short4*>(&Bh[(ng*4+0)*40 + kq*4]) = hj;
      *reinterpret_cast<short4*>(&Bl[(ng*4+0)*40 + kq*4]) = lj;
      split2(v0.y,hj.x,lj.x); split2(v1.y,hj.y,lj.y); split2(v2.y,hj.z,lj.z); split2(v3.y,hj.w,lj.w);
      *reinterpret_cast<short4*>(&Bh[(ng*4+1)*40 + kq*4]) = hj;
      *reinterpret_cast<short4*>(&Bl[(ng*4+1)*40 + kq*4]) = lj;
      split2(v0.z,hj.x,lj.x); split2(v1.z,hj.y,lj.y); split2(v2.z,hj.z,lj.z); split2(v3.z,hj.w,lj.w);
      *reinterpret_cast<short4*>(&Bh[(ng*4+2)*40 + kq*4]) = hj;
      *reinterpret_cast<short4*>(&Bl[(ng*4+2)*40 + kq*4]) = lj;
      split2(v0.w,hj.x,lj.x); split2(v1.w,hj.y,lj.y); split2(v2.w,hj.z,lj.z); split2(v3.w,hj.w,lj.w);
      *reinterpret_cast<short4*>(&Bh[(ng*4+3)*40 + kq*4]) = hj;
      *reinterpret_cast<short4*>(&Bl[(ng*4+3)*40 + kq*4]) = lj;
    }
    __syncthreads();
    bf16x8 ah[2], al[2], bh[4], bl[4];
    #pragma unroll
    for (int mi=0;mi<2;mi++) {
      ah[mi] = *reinterpret_cast<const bf16x8*>(&Ah[(wm2*32+mi*16+lk)*40 + lg*8]);
      al[mi] = *reinterpret_cast<const bf16x8*>(&Al[(wm2*32+mi*16+lk)*40 + lg*8]);
    }
    #pragma unroll
    for (int nj=0;nj<4;nj++) {
      bh[nj] = *reinterpret_cast<const bf16x8*>(&Bh[(wn2*64+nj*16+lk)*40 + lg*8]);
      bl[nj] = *reinterpret_cast<const bf16x8*>(&Bl[(wn2*64+nj*16+lk)*40 + lg*8]);
    }
    #pragma unroll
    for (int mi=0;mi<2;mi++)
      #pragma unroll
      for (int nj=0;nj<4;nj++) {
        acc[mi][nj] = __builtin_amdgcn_mfma_f32_16x16x32_bf16(ah[mi], bh[nj], acc[mi][nj], 0, 0, 0);
        acc[mi][nj] = __builtin_amdgcn_mfma_f32_16x16x32_bf16(ah[mi], bl[nj], acc[mi][nj], 0, 0, 0);
        acc[mi][nj] = __builtin_amdgcn_mfma_f32_16x16x32_bf16(al[mi], bh[nj], acc[mi][nj], 0, 0, 0);
      }
    __syncthreads();
  }
  #pragma unroll
  for (int mi=0;mi<2;mi++)
    #pragma unroll
    for (int nj=0;nj<4;nj++)
      #pragma unroll
      for (int r=0;r<4;r++)
        Cp[((size_t)kc*64 + wm2*32 + mi*16 + lg*4 + r)*N + n0 + wn2*64 + nj*16 + lk] = acc[mi][nj][r];
}

// ---------------- M64 x N(64-tile) GEMM via MFMA: A split bf16x2, B EXACT bf16 ----------------
__global__ __launch_bounds__(256) void gemm64x64_mfma(const float* __restrict__ A, int lda,
    const float* __restrict__ Bw, int ldb, int Bhstride,
    const float* __restrict__ scl, float smul,
    float* __restrict__ out, int ostride, int ohstride, int okcstride, int nk128) {
  __shared__ __align__(16) short Ah[64*136], Al[64*136], Bh[64*136];  // [row][k128] stride 136
  const int t = threadIdx.x;
  const int h = blockIdx.x, ct = blockIdx.y, kcz = blockIdx.z;
  const int koffs = kcz*nk128*128;
  const int lane = t & 63, wid = t >> 6;
  const int lk = lane & 15, lg = lane >> 4;
  const int wm2 = wid >> 1, wn2 = wid & 1;
  const int H = gridDim.x;
  f32x4 acc[2][2];
  #pragma unroll
  for (int mi=0;mi<2;mi++)
    #pragma unroll
    for (int nj=0;nj<2;nj++) acc[mi][nj] = (f32x4){0.f,0.f,0.f,0.f};

  for (int c=0; c<nk128; ++c) {
    if (c) __syncthreads();
    const int k0 = koffs + c*128;
    #pragma unroll
    for (int l=0;l<8;l++) {
      int idx = t + l*256;           // 64 rows x 32 quads = 2048
      int m = idx >> 5, kq = idx & 31;
      float4 v = ld4(&A[((size_t)m*H + h)*lda + k0 + kq*4]);
      short4 h4, l4;
      split2(v.x,h4.x,l4.x); split2(v.y,h4.y,l4.y);
      split2(v.z,h4.z,l4.z); split2(v.w,h4.w,l4.w);
      *reinterpret_cast<short4*>(&Ah[m*136 + kq*4]) = h4;
      *reinterpret_cast<short4*>(&Al[m*136 + kq*4]) = l4;
      float4 w = ld4(&Bw[(size_t)h*Bhstride + (size_t)(ct*64 + m)*ldb + k0 + kq*4]);
      short4 b4; b4.x=f2b(w.x); b4.y=f2b(w.y); b4.z=f2b(w.z); b4.w=f2b(w.w);  // exact
      *reinterpret_cast<short4*>(&Bh[m*136 + kq*4]) = b4;
    }
    __syncthreads();
    #pragma unroll
    for (int ks=0; ks<4; ++ks) {
      bf16x8 ah[2], al[2], bh[2];
      #pragma unroll
      for (int mi=0;mi<2;mi++) {
        ah[mi] = *reinterpret_cast<const bf16x8*>(&Ah[(wm2*32+mi*16+lk)*136 + ks*32 + lg*8]);
        al[mi] = *reinterpret_cast<const bf16x8*>(&Al[(wm2*32+mi*16+lk)*136 + ks*32 + lg*8]);
      }
      #pragma unroll
      for (int nj=0;nj<2;nj++)
        bh[nj] = *reinterpret_cast<const bf16x8*>(&Bh[(wn2*32+nj*16+lk)*136 + ks*32 + lg*8]);
      #pragma unroll
      for (int mi=0;mi<2;mi++)
        #pragma unroll
        for (int nj=0;nj<2;nj++) {
          acc[mi][nj] = __builtin_amdgcn_mfma_f32_16x16x32_bf16(ah[mi], bh[nj], acc[mi][nj], 0, 0, 0);
          acc[mi][nj] = __builtin_amdgcn_mfma_f32_16x16x32_bf16(al[mi], bh[nj], acc[mi][nj], 0, 0, 0);
        }
    }
  }
  const float sc = scl[0]*smul;
  #pragma unroll
  for (int mi=0;mi<2;mi++)
    #pragma unroll
    for (int nj=0;nj<2;nj++)
      #pragma unroll
      for (int r=0;r<4;r++) {
        int row = wm2*32 + mi*16 + lg*4 + r;
        int col = ct*64 + wn2*32 + nj*16 + lk;
        out[(size_t)kcz*okcstride + (size_t)row*ostride + (size_t)h*ohstride + col] = acc[mi][nj][r]*sc;
      }
}

// ---------------- reduce q partials + split nope/pe + rope ----------------
__global__ __launch_bounds__(256) void reduce_rope(const float* __restrict__ qp,
    const int* __restrict__ positions, float* __restrict__ qn, float* __restrict__ qfull) {
  __shared__ float pe[H_*ROPE_];
  const int b = blockIdx.x, t = threadIdx.x;
  for (int n = t*4; n < NQ_; n += 1024) {
    float4 s = make_float4(0.f,0.f,0.f,0.f);
    for (int c=0;c<KCH_;c++) {
      float4 v = ld4(&qp[((size_t)c*64 + b)*NQ_ + n]);
      s.x+=v.x; s.y+=v.y; s.z+=v.z; s.w+=v.w;
    }
    float vs[4] = {s.x,s.y,s.z,s.w};
    #pragma unroll
    for (int e=0;e<4;e++) {
      int nn = n+e; int h = nn/DQ_; int d = nn - h*DQ_;
      if (d < NOPE_) qn[((size_t)b*H_ + h)*NOPE_ + d] = vs[e];
      else pe[h*ROPE_ + (d-NOPE_)] = vs[e];
    }
  }
  __syncthreads();
  const float pos = (float)positions[b];
  const float SC = 0.0721687836487032f; // 1/sqrt(192)
  for (int it = t; it < H_*32; it += 256) {
    int h = it >> 5, i = it & 31;
    float invf = (float)exp(-(double)i * 0.28782313662425574); // 10000^(-i/32)
    float fr = pos * invf;
    float cs = cosf(fr), sn = sinf(fr);
    float q1 = pe[h*ROPE_ + i], q2 = pe[h*ROPE_ + 32 + i];
    qfull[((size_t)b*H_ + h)*DKV_ + R_ + i]      = (q1*cs - q2*sn)*SC;
    qfull[((size_t)b*H_ + h)*DKV_ + R_ + 32 + i] = (q2*cs + q1*sn)*SC;
  }
}

// ---------------- flash-decode attention chunk: 2 barriers/iter (PV folded into next A) ----
__global__ __launch_bounds__(256) void attn_chunk(const float* __restrict__ qfull,
    const float* __restrict__ kv, const int* __restrict__ topk,
    float* __restrict__ om, float* __restrict__ ol, float* __restrict__ op) {
  __shared__ __align__(16) short krows[2][KRSZ_];     // 2 x 19,008 B
  __shared__ __align__(16) short P_lds[H_*VTS_];      // 1,536 B
  __shared__ float Spart[2*16*33];                    // 4,224 B
  __shared__ float fl[H_];
  __shared__ int tk_lds[CHUNK_];
  const int lin = blockIdx.x + 8*blockIdx.y;   // [0,512)
  const int xcd = lin & 7, ixc = lin >> 3;
  const int b  = xcd*8 + (ixc & 7);            // same-b blocks share an XCD slot
  const int kc = ixc >> 3;
  const int t = threadIdx.x;
  const int lane = t & 63, wid = t >> 6;
  const int wm = wid >> 1, dn = wid & 1;   // score role: head-block, d-half
  const int lk = lane & 15, lg = lane >> 4;
  const int l31 = lane & 31, hi = lane >> 5;
  const int h16 = wm*16 + lk;

  bf16x8 qf[9];
  {
    const float* qb = &qfull[((size_t)b*H_ + h16)*DKV_ + dn*288 + lg*8];
    #pragma unroll
    for (int ks=0; ks<9; ++ks) {
      float4 u = ld4(qb + ks*32);
      float4 v = ld4(qb + ks*32 + 4);
      bf16x8 f;
      f[0]=f2b(u.x); f[1]=f2b(u.y); f[2]=f2b(u.z); f[3]=f2b(u.w);
      f[4]=f2b(v.x); f[5]=f2b(v.y); f[6]=f2b(v.z); f[7]=f2b(v.w);
      qf[ks] = f;
    }
  }

  int row_l[9], coff_l[9], woff_l[9];
  #pragma unroll
  for (int l=0;l<9;l++) {
    int idx = t + l*256;                 // 16*144 = 2304 = 9*256
    int row = idx/144, c = idx - row*144;
    int d0 = c*4;
    row_l[l] = row; coff_l[l] = d0;
    woff_l[l] = (d0>>4)*DGSTR_ + row*16 + (d0&15);
  }
  const float* kvb = kv + (size_t)b*S_*DKV_;
  const int kbase = b*TOPK_ + kc*CHUNK_;
  tk_lds[t] = topk[kbase + t];
  __syncthreads();

  float4 stA[9], stB[9];
  #define ISSUE(ST, G) { \
    _Pragma("unroll") \
    for (int l=0;l<9;l++) { \
      int ki = tk_lds[(G)*TILE_ + row_l[l]]; \
      ST[l] = ld4(kvb + (size_t)ki*DKV_ + coff_l[l]); \
    } }
  #define WBUF(KB, ST) { \
    _Pragma("unroll") \
    for (int l=0;l<9;l++) { \
      short4 s4; s4.x=f2b(ST[l].x); s4.y=f2b(ST[l].y); s4.z=f2b(ST[l].z); s4.w=f2b(ST[l].w); \
      *reinterpret_cast<short4*>(&(KB)[woff_l[l]]) = s4; \
    } }

  ISSUE(stA, 0);
  WBUF(krows[0], stA);
  ISSUE(stA, 1);
  ISSUE(stB, 2);
  asm volatile("s_waitcnt lgkmcnt(0)\n\ts_barrier" ::: "memory");

  float m_run = -INFINITY, l_run = 0.f;
  f32x16 acc[4];
  #pragma unroll
  for (int tt=0;tt<4;tt++)
    #pragma unroll
    for (int i=0;i<16;i++) acc[tt][i] = 0.f;

  const int soff = (dn*18 + (lg>>1))*DGSTR_ + lk*16 + (lg&1)*8;
  const int i15 = lk;
  const unsigned trc = (unsigned)((((wid*8) + ((lane>>4)&1))*DGSTR_ + (hi*8 + (i15>>2))*16 + (i15&3)*4)*2);

  #define PVBLOCK(KBP) { \
    float fsc = fl[l31]; \
    bf16x8 pf = *reinterpret_cast<const bf16x8*>(&P_lds[l31*VTS_ + hi*8]); \
    unsigned kaddr = (unsigned)(unsigned long long)(void*)(KBP); \
    s16x4 tr0_0 = tr_read(kaddr + trc + 0*1056); \
    s16x4 tr1_0 = tr_read(kaddr + trc + 0*1056 + 128); \
    s16x4 tr0_1 = tr_read(kaddr + trc + 1*1056); \
    s16x4 tr1_1 = tr_read(kaddr + trc + 1*1056 + 128); \
    s16x4 tr0_2 = tr_read(kaddr + trc + 2*1056); \
    s16x4 tr1_2 = tr_read(kaddr + trc + 2*1056 + 128); \
    s16x4 tr0_3 = tr_read(kaddr + trc + 3*1056); \
    s16x4 tr1_3 = tr_read(kaddr + trc + 3*1056 + 128); \
    _Pragma("unroll") \
    for (int tt=0;tt<4;tt++) \
      _Pragma("unroll") \
      for (int i=0;i<16;i++) acc[tt][i] *= fsc; \
    asm volatile("s_waitcnt lgkmcnt(0)" ::: "memory"); \
    __builtin_amdgcn_sched_barrier(0); \
    bf16x8 vf; \
    vf[0]=tr0_0[0]; vf[1]=tr0_0[1]; vf[2]=tr0_0[2]; vf[3]=tr0_0[3]; \
    vf[4]=tr1_0[0]; vf[5]=tr1_0[1]; vf[6]=tr1_0[2]; vf[7]=tr1_0[3]; \
    acc[0] = __builtin_amdgcn_mfma_f32_32x32x16_bf16(vf, pf, acc[0], 0, 0, 0); \
    vf[0]=tr0_1[0]; vf[1]=tr0_1[1]; vf[2]=tr0_1[2]; vf[3]=tr0_1[3]; \
    vf[4]=tr1_1[0]; vf[5]=tr1_1[1]; vf[6]=tr1_1[2]; vf[7]=tr1_1[3]; \
    acc[1] = __builtin_amdgcn_mfma_f32_32x32x16_bf16(vf, pf, acc[1], 0, 0, 0); \
    vf[0]=tr0_2[0]; vf[1]=tr0_2[1]; vf[2]=tr0_2[2]; vf[3]=tr0_2[3]; \
    vf[4]=tr1_2[0]; vf[5]=tr1_2[1]; vf[6]=tr1_2[2]; vf[7]=tr1_2[3]; \
    acc[2] = __builtin_amdgcn_mfma_f32_32x32x16_bf16(vf, pf, acc[2], 0, 0, 0); \
    vf[0]=tr0_3[0]; vf[1]=tr0_3[1]; vf[2]=tr0_3[2]; vf[3]=tr0_3[3]; \
    vf[4]=tr1_3[0]; vf[5]=tr1_3[1]; vf[6]=tr1_3[2]; vf[7]=tr1_3[3]; \
    acc[3] = __builtin_amdgcn_mfma_f32_32x32x16_bf16(vf, pf, acc[3], 0, 0, 0); \
  }

  for (int g=0; g<NG_; ++g) {
    const int cur = g & 1;
    short* kb  = krows[cur];
    short* kbp = krows[cur^1];   // tile g-1 (valid for g>=1)

    // ---- phase A': scores(g) + (g>0) PV(g-1) ----
    f32x4 sacc = {0.f,0.f,0.f,0.f};
    #pragma unroll
    for (int ks=0; ks<9; ++ks) {
      bf16x8 af = *reinterpret_cast<const bf16x8*>(&kb[soff + ks*(2*DGSTR_)]);
      sacc = __builtin_amdgcn_mfma_f32_16x16x32_bf16(af, qf[ks], sacc, 0, 0, 0);
    }
    if (g) PVBLOCK(kbp);
    #pragma unroll
    for (int r=0;r<4;r++)
      Spart[dn*528 + (lg*4+r)*33 + h16] = sacc[r];
    asm volatile("s_waitcnt lgkmcnt(0)\n\ts_barrier" ::: "memory");

    // ---- phase B: softmax + P/fl write + staged LDS write (tile g+1) + issue (tile g+3) ----
    float sfull[4];
    #pragma unroll
    for (int r=0;r<4;r++)
      sfull[r] = Spart[(lg*4+r)*33 + h16] + Spart[528 + (lg*4+r)*33 + h16];
    float tmax = fmaxf(fmaxf(sfull[0],sfull[1]), fmaxf(sfull[2],sfull[3]));
    tmax = fmaxf(tmax, __shfl_xor(tmax, 16));
    tmax = fmaxf(tmax, __shfl_xor(tmax, 32));
    float m_new = fmaxf(m_run, tmax);
    float fscale = __expf(m_run - m_new);
    m_run = m_new;
    float p0 = __expf(sfull[0]-m_new), p1 = __expf(sfull[1]-m_new);
    float p2 = __expf(sfull[2]-m_new), p3 = __expf(sfull[3]-m_new);
    float ps = (p0+p1)+(p2+p3);
    ps += __shfl_xor(ps, 16);
    ps += __shfl_xor(ps, 32);
    l_run = l_run*fscale + ps;
    if (dn==0) {
      short4 pk; pk.x=f2b(p0); pk.y=f2b(p1); pk.z=f2b(p2); pk.w=f2b(p3);
      *reinterpret_cast<short4*>(&P_lds[h16*VTS_ + lg*4]) = pk;
      if (lg==0) fl[h16] = fscale;
    }
    if ((g & 1) == 0) {
      if (g < NG_-1) WBUF(krows[cur^1], stA);
      if (g+3 < NG_) ISSUE(stA, g+3);
    } else {
      if (g < NG_-1) WBUF(krows[cur^1], stB);
      if (g+3 < NG_) ISSUE(stB, g+3);
    }
    asm volatile("s_waitcnt lgkmcnt(0)\n\ts_barrier" ::: "memory");
  }

  // epilogue: PV for tile NG-1 (krows[(NG_-1)&1], P_lds/fl from last B)
  PVBLOCK(krows[(NG_-1)&1]);

  if (dn==0 && lg==0) {
    om[(b*ACH_+kc)*H_ + h16] = m_run;
    ol[(b*ACH_+kc)*H_ + h16] = l_run;
  }
  #pragma unroll
  for (int tt=0;tt<4;tt++)
    #pragma unroll
    for (int q=0;q<4;q++) {
      float4 v = make_float4(acc[tt][4*q+0], acc[tt][4*q+1], acc[tt][4*q+2], acc[tt][4*q+3]);
      int r0 = wid*128 + tt*32 + 8*q + 4*hi;
      *reinterpret_cast<float4*>(&op[(((size_t)(b*ACH_+kc))*H_ + l31)*R_ + r0]) = v;
    }
  #undef ISSUE
  #undef WBUF
  #undef PVBLOCK
}

// ---------------- merge chunk partials ----------------
__global__ __launch_bounds__(128) void attn_merge(const float* __restrict__ om,
    const float* __restrict__ ol, const float* __restrict__ op, float* __restrict__ obuf) {
  const int bh = blockIdx.x;
  const int b = bh >> 5, h = bh & 31;
  const int t = threadIdx.x;
  float mv[8], lv[8], w[8];
  float M = -INFINITY;
  #pragma unroll
  for (int c=0;c<8;c++) { mv[c] = om[(b*ACH_+c)*H_ + h]; lv[c] = ol[(b*ACH_+c)*H_+h]; M = fmaxf(M, mv[c]); }
  float L = 0.f;
  #pragma unroll
  for (int c=0;c<8;c++) { w[c] = __expf(mv[c]-M); L += lv[c]*w[c]; }
  float inv = 1.0f / L;
  float4 s = make_float4(0.f,0.f,0.f,0.f);
  #pragma unroll
  for (int c=0;c<8;c++) {
    float4 v = ld4(&op[(((size_t)(b*ACH_+c))*H_ + h)*R_ + t*4]);
    s.x += v.x*w[c]; s.y += v.y*w[c]; s.z += v.z*w[c]; s.w += v.w*w[c];
  }
  s.x*=inv; s.y*=inv; s.z*=inv; s.w*=inv;
  *reinterpret_cast<float4*>(&obuf[((size_t)b*H_+h)*R_ + t*4]) = s;
}

// ---------------- final reduce of Wo partials (KCHO_) ----------------
__global__ __launch_bounds__(256) void reduce_out(const float* __restrict__ op2, float* __restrict__ out) {
  int idx = blockIdx.x*256 + threadIdx.x; // float4 index
  float4 s = make_float4(0.f,0.f,0.f,0.f);
  #pragma unroll
  for (int c=0;c<KCHO_;c++) {
    float4 v = ld4(&op2[(size_t)c*B_*HID_ + (size_t)idx*4]);
    s.x+=v.x; s.y+=v.y; s.z+=v.z; s.w+=v.w;
  }
  *reinterpret_cast<float4*>(&out[(size_t)idx*4]) = s;
}

extern "C" void kernel_launch(void* const* d_in, const int* in_sizes, int n_in,
                              void* d_out, int out_size, void* d_ws, size_t ws_size,
                              hipStream_t stream) {
  (void)in_sizes; (void)n_in; (void)out_size; (void)ws_size;
  const float* x   = (const float*)d_in[0];
  const float* Wq  = (const float*)d_in[1];
  const float* WK  = (const float*)d_in[2];
  const float* WKs = (const float*)d_in[3];
  const float* WV  = (const float*)d_in[4];
  const float* WVs = (const float*)d_in[5];
  const float* Wo  = (const float*)d_in[6];
  const float* kv  = (const float*)d_in[7];
  const int* topk  = (const int*)d_in[8];
  const int* pos   = (const int*)d_in[9];
  float* ws = (float*)d_ws;
  float* qp    = ws;                                   // 16*64*6144   = 6,291,456
  float* qn    = qp    + (size_t)KCH_*64*6144;         // 64*32*128    =   262,144
  float* qfull = qn    + (size_t)64*32*128;            // 64*32*576    = 1,179,648
  float* om    = qfull + (size_t)64*32*576;            // 64*8*32
  float* ol    = om    + (size_t)64*8*32;              // 64*8*32
  float* op    = ol    + (size_t)64*8*32;              // 64*8*32*512  = 8,388,608
  float* obuf  = op    + (size_t)64*8*32*512;          // 64*32*512    = 1,048,576
  float* midp  = obuf  + (size_t)64*32*512;            // 2*64*4096    =   524,288
  float* op2   = midp  + (size_t)2*64*4096;            // 8*64*4096    = 2,097,152
  float* outf  = (float*)d_out;
  const float SC = 0.0721687836487032f; // 1/sqrt(192)

  gemm64_mfma<<<dim3(48,KCH_),256,0,stream>>>(x, nullptr, Wq, qp, NQ_, HID_);
  reduce_rope<<<64,256,0,stream>>>(qp, pos, qn, qfull);
  // ql = q_nope @ W_K[h]^T * (WKs*SC) -> qfull[:, :, 0:512]
  gemm64x64_mfma<<<dim3(32,8,1),256,0,stream>>>(qn, NOPE_, WK, NOPE_, R_*NOPE_,
      WKs, SC, qfull, H_*DKV_, DKV_, 0, 1);
  attn_chunk<<<dim3(8,64),256,0,stream>>>(qfull, kv, topk, om, ol, op);
  attn_merge<<<2048,128,0,stream>>>(om, ol, op, obuf);
  // vproj partials: mid_p[kc] = o @ W_V[h]^T * WVs over K-half kc
  gemm64x64_mfma<<<dim3(32,2,2),256,0,stream>>>(obuf, R_, WV, R_, V_*R_,
      WVs, 1.0f, midp, HID_, V_, B_*HID_, 2);
  // out partials: (mid_p0 + mid_p1) @ Wo, KCHO_=8 K-chunks (halved op2 traffic)
  gemm64_mfma<<<dim3(32,KCHO_),256,0,stream>>>(midp, midp + (size_t)B_*HID_, Wo, op2, HID_, HID_);
  reduce_out<<<256,256,0,stream>>>(op2, outf);
}

// Round 20
// 179.178 us; speedup vs baseline: 1.0574x; 1.0574x over previous
//
#include <hip/hip_runtime.h>
#include <hip/hip_bf16.h>
#include <math.h>

#define H_ 32
#define R_ 512
#define NOPE_ 128
#define ROPE_ 64
#define V_ 128
#define HID_ 4096
#define B_ 64
#define S_ 4096
#define TOPK_ 2048
#define DQ_ 192      // NOPE+ROPE
#define NQ_ 6144     // H*DQ
#define DKV_ 576     // R+ROPE
#define KCH_ 16      // K-chunks for skinny GEMMs (r19 lesson: 512 blocks = 2/CU beats traffic savings)
#define ACH_ 8       // attention k-chunks
#define CHUNK_ 256   // TOPK/ACH
#define TILE_ 16     // gathered rows per inner iteration
#define NG_ (CHUNK_/TILE_)   // 16 inner iterations
#define DGSTR_ 264   // krows dgrp stride in shorts (16key*16d = 256 + 8 pad)
#define KRSZ_ (36*DGSTR_)    // shorts per buffer
#define VTS_ 24      // P_lds stride (shorts)

typedef __attribute__((ext_vector_type(8))) short bf16x8;
typedef __attribute__((ext_vector_type(4))) short s16x4;
typedef __attribute__((ext_vector_type(4))) float f32x4;
typedef __attribute__((ext_vector_type(16))) float f32x16;

__device__ __forceinline__ float4 ld4(const float* p) { return *reinterpret_cast<const float4*>(p); }
__device__ __forceinline__ short f2b(float f) {
  __hip_bfloat16 h = __float2bfloat16(f);
  short s; __builtin_memcpy(&s, &h, 2); return s;
}
__device__ __forceinline__ float b2f(short s) {
  union { unsigned u; float f; } x; x.u = ((unsigned)(unsigned short)s) << 16; return x.f;
}
__device__ __forceinline__ void split2(float v, short& h, short& l) {
  short hh = f2b(v);
  h = hh; l = f2b(v - b2f(hh));
}
__device__ __forceinline__ s16x4 tr_read(unsigned byte_addr) {
  s16x4 r;
  asm volatile("ds_read_b64_tr_b16 %0, %1" : "=v"(r) : "v"(byte_addr));
  return r;
}

// ---------------- skinny partial GEMM via MFMA bf16x3 (f32-class precision) ----------------
__global__ __launch_bounds__(256) void gemm64_mfma(const float* __restrict__ A,
    const float* __restrict__ A2,
    const float* __restrict__ Bm, float* __restrict__ Cp, int N, int K) {
  __shared__ __align__(16) short Ah[64*40], Al[64*40];   // [m][k32] stride 40
  __shared__ __align__(16) short Bh[128*40], Bl[128*40]; // [n][k32] stride 40
  const int t = threadIdx.x;
  const int nt = blockIdx.x, kc = blockIdx.y;
  const int n0 = nt*128;
  const int kchunk = K / gridDim.y, kbeg = kc*kchunk;
  const int lane = t & 63, wid = t >> 6;
  const int lk = lane & 15, lg = lane >> 4;
  const int wm2 = wid >> 1, wn2 = wid & 1;   // m-half(32), n-half(64)
  const int kq = t & 7, ng = t >> 3;         // B-transpose ownership
  f32x4 acc[2][4];
  #pragma unroll
  for (int mi=0;mi<2;mi++)
    #pragma unroll
    for (int nj=0;nj<4;nj++) acc[mi][nj] = (f32x4){0.f,0.f,0.f,0.f};

  for (int k0 = kbeg; k0 < kbeg + kchunk; k0 += 32) {
    #pragma unroll
    for (int l=0;l<2;l++) {
      int idx = t + l*256;
      int m = idx >> 3, kq2 = idx & 7;
      float4 v = ld4(&A[(size_t)m*K + k0 + kq2*4]);
      if (A2) {
        float4 w = ld4(&A2[(size_t)m*K + k0 + kq2*4]);
        v.x+=w.x; v.y+=w.y; v.z+=w.z; v.w+=w.w;
      }
      short4 h4, l4;
      split2(v.x, h4.x, l4.x); split2(v.y, h4.y, l4.y);
      split2(v.z, h4.z, l4.z); split2(v.w, h4.w, l4.w);
      *reinterpret_cast<short4*>(&Ah[m*40 + kq2*4]) = h4;
      *reinterpret_cast<short4*>(&Al[m*40 + kq2*4]) = l4;
    }
    {
      float4 v0 = ld4(&Bm[(size_t)(k0+kq*4+0)*N + n0 + ng*4]);
      float4 v1 = ld4(&Bm[(size_t)(k0+kq*4+1)*N + n0 + ng*4]);
      float4 v2 = ld4(&Bm[(size_t)(k0+kq*4+2)*N + n0 + ng*4]);
      float4 v3 = ld4(&Bm[(size_t)(k0+kq*4+3)*N + n0 + ng*4]);
      short4 hj, lj;
      split2(v0.x,hj.x,lj.x); split2(v1.x,hj.y,lj.y); split2(v2.x,hj.z,lj.z); split2(v3.x,hj.w,lj.w);
      *reinterpret_cast<short4*>(&Bh[(ng*4+0)*40 + kq*4]) = hj;
      *reinterpret_cast<short4*>(&Bl[(ng*4+0)*40 + kq*4]) = lj;
      split2(v0.y,hj.x,lj.x); split2(v1.y,hj.y,lj.y); split2(v2.y,hj.z,lj.z); split2(v3.y,hj.w,lj.w);
      *reinterpret_cast<short4*>(&Bh[(ng*4+1)*40 + kq*4]) = hj;
      *reinterpret_cast<short4*>(&Bl[(ng*4+1)*40 + kq*4]) = lj;
      split2(v0.z,hj.x,lj.x); split2(v1.z,hj.y,lj.y); split2(v2.z,hj.z,lj.z); split2(v3.z,hj.w,lj.w);
      *reinterpret_cast<short4*>(&Bh[(ng*4+2)*40 + kq*4]) = hj;
      *reinterpret_cast<short4*>(&Bl[(ng*4+2)*40 + kq*4]) = lj;
      split2(v0.w,hj.x,lj.x); split2(v1.w,hj.y,lj.y); split2(v2.w,hj.z,lj.z); split2(v3.w,hj.w,lj.w);
      *reinterpret_cast<short4*>(&Bh[(ng*4+3)*40 + kq*4]) = hj;
      *reinterpret_cast<short4*>(&Bl[(ng*4+3)*40 + kq*4]) = lj;
    }
    __syncthreads();
    bf16x8 ah[2], al[2], bh[4], bl[4];
    #pragma unroll
    for (int mi=0;mi<2;mi++) {
      ah[mi] = *reinterpret_cast<const bf16x8*>(&Ah[(wm2*32+mi*16+lk)*40 + lg*8]);
      al[mi] = *reinterpret_cast<const bf16x8*>(&Al[(wm2*32+mi*16+lk)*40 + lg*8]);
    }
    #pragma unroll
    for (int nj=0;nj<4;nj++) {
      bh[nj] = *reinterpret_cast<const bf16x8*>(&Bh[(wn2*64+nj*16+lk)*40 + lg*8]);
      bl[nj] = *reinterpret_cast<const bf16x8*>(&Bl[(wn2*64+nj*16+lk)*40 + lg*8]);
    }
    #pragma unroll
    for (int mi=0;mi<2;mi++)
      #pragma unroll
      for (int nj=0;nj<4;nj++) {
        acc[mi][nj] = __builtin_amdgcn_mfma_f32_16x16x32_bf16(ah[mi], bh[nj], acc[mi][nj], 0, 0, 0);
        acc[mi][nj] = __builtin_amdgcn_mfma_f32_16x16x32_bf16(ah[mi], bl[nj], acc[mi][nj], 0, 0, 0);
        acc[mi][nj] = __builtin_amdgcn_mfma_f32_16x16x32_bf16(al[mi], bh[nj], acc[mi][nj], 0, 0, 0);
      }
    __syncthreads();
  }
  #pragma unroll
  for (int mi=0;mi<2;mi++)
    #pragma unroll
    for (int nj=0;nj<4;nj++)
      #pragma unroll
      for (int r=0;r<4;r++)
        Cp[((size_t)kc*64 + wm2*32 + mi*16 + lg*4 + r)*N + n0 + wn2*64 + nj*16 + lk] = acc[mi][nj][r];
}

// ---------------- M64 x N(64-tile) GEMM via MFMA: A split bf16x2, B EXACT bf16 ----------------
__global__ __launch_bounds__(256) void gemm64x64_mfma(const float* __restrict__ A, int lda,
    const float* __restrict__ Bw, int ldb, int Bhstride,
    const float* __restrict__ scl, float smul,
    float* __restrict__ out, int ostride, int ohstride, int okcstride, int nk128) {
  __shared__ __align__(16) short Ah[64*136], Al[64*136], Bh[64*136];  // [row][k128] stride 136
  const int t = threadIdx.x;
  const int h = blockIdx.x, ct = blockIdx.y, kcz = blockIdx.z;
  const int koffs = kcz*nk128*128;
  const int lane = t & 63, wid = t >> 6;
  const int lk = lane & 15, lg = lane >> 4;
  const int wm2 = wid >> 1, wn2 = wid & 1;
  const int H = gridDim.x;
  f32x4 acc[2][2];
  #pragma unroll
  for (int mi=0;mi<2;mi++)
    #pragma unroll
    for (int nj=0;nj<2;nj++) acc[mi][nj] = (f32x4){0.f,0.f,0.f,0.f};

  for (int c=0; c<nk128; ++c) {
    if (c) __syncthreads();
    const int k0 = koffs + c*128;
    #pragma unroll
    for (int l=0;l<8;l++) {
      int idx = t + l*256;           // 64 rows x 32 quads = 2048
      int m = idx >> 5, kq = idx & 31;
      float4 v = ld4(&A[((size_t)m*H + h)*lda + k0 + kq*4]);
      short4 h4, l4;
      split2(v.x,h4.x,l4.x); split2(v.y,h4.y,l4.y);
      split2(v.z,h4.z,l4.z); split2(v.w,h4.w,l4.w);
      *reinterpret_cast<short4*>(&Ah[m*136 + kq*4]) = h4;
      *reinterpret_cast<short4*>(&Al[m*136 + kq*4]) = l4;
      float4 w = ld4(&Bw[(size_t)h*Bhstride + (size_t)(ct*64 + m)*ldb + k0 + kq*4]);
      short4 b4; b4.x=f2b(w.x); b4.y=f2b(w.y); b4.z=f2b(w.z); b4.w=f2b(w.w);  // exact
      *reinterpret_cast<short4*>(&Bh[m*136 + kq*4]) = b4;
    }
    __syncthreads();
    #pragma unroll
    for (int ks=0; ks<4; ++ks) {
      bf16x8 ah[2], al[2], bh[2];
      #pragma unroll
      for (int mi=0;mi<2;mi++) {
        ah[mi] = *reinterpret_cast<const bf16x8*>(&Ah[(wm2*32+mi*16+lk)*136 + ks*32 + lg*8]);
        al[mi] = *reinterpret_cast<const bf16x8*>(&Al[(wm2*32+mi*16+lk)*136 + ks*32 + lg*8]);
      }
      #pragma unroll
      for (int nj=0;nj<2;nj++)
        bh[nj] = *reinterpret_cast<const bf16x8*>(&Bh[(wn2*32+nj*16+lk)*136 + ks*32 + lg*8]);
      #pragma unroll
      for (int mi=0;mi<2;mi++)
        #pragma unroll
        for (int nj=0;nj<2;nj++) {
          acc[mi][nj] = __builtin_amdgcn_mfma_f32_16x16x32_bf16(ah[mi], bh[nj], acc[mi][nj], 0, 0, 0);
          acc[mi][nj] = __builtin_amdgcn_mfma_f32_16x16x32_bf16(al[mi], bh[nj], acc[mi][nj], 0, 0, 0);
        }
    }
  }
  const float sc = scl[0]*smul;
  #pragma unroll
  for (int mi=0;mi<2;mi++)
    #pragma unroll
    for (int nj=0;nj<2;nj++)
      #pragma unroll
      for (int r=0;r<4;r++) {
        int row = wm2*32 + mi*16 + lg*4 + r;
        int col = ct*64 + wn2*32 + nj*16 + lk;
        out[(size_t)kcz*okcstride + (size_t)row*ostride + (size_t)h*ohstride + col] = acc[mi][nj][r]*sc;
      }
}

// ---------------- reduce q partials + split nope/pe + rope ----------------
__global__ __launch_bounds__(256) void reduce_rope(const float* __restrict__ qp,
    const int* __restrict__ positions, float* __restrict__ qn, float* __restrict__ qfull) {
  __shared__ float pe[H_*ROPE_];
  const int b = blockIdx.x, t = threadIdx.x;
  for (int n = t*4; n < NQ_; n += 1024) {
    float4 s = make_float4(0.f,0.f,0.f,0.f);
    for (int c=0;c<KCH_;c++) {
      float4 v = ld4(&qp[((size_t)c*64 + b)*NQ_ + n]);
      s.x+=v.x; s.y+=v.y; s.z+=v.z; s.w+=v.w;
    }
    float vs[4] = {s.x,s.y,s.z,s.w};
    #pragma unroll
    for (int e=0;e<4;e++) {
      int nn = n+e; int h = nn/DQ_; int d = nn - h*DQ_;
      if (d < NOPE_) qn[((size_t)b*H_ + h)*NOPE_ + d] = vs[e];
      else pe[h*ROPE_ + (d-NOPE_)] = vs[e];
    }
  }
  __syncthreads();
  const float pos = (float)positions[b];
  const float SC = 0.0721687836487032f; // 1/sqrt(192)
  for (int it = t; it < H_*32; it += 256) {
    int h = it >> 5, i = it & 31;
    float invf = (float)exp(-(double)i * 0.28782313662425574); // 10000^(-i/32)
    float fr = pos * invf;
    float cs = cosf(fr), sn = sinf(fr);
    float q1 = pe[h*ROPE_ + i], q2 = pe[h*ROPE_ + 32 + i];
    qfull[((size_t)b*H_ + h)*DKV_ + R_ + i]      = (q1*cs - q2*sn)*SC;
    qfull[((size_t)b*H_ + h)*DKV_ + R_ + 32 + i] = (q2*cs + q1*sn)*SC;
  }
}

// ---------------- flash-decode attention chunk: 2 barriers/iter (PV folded into next A) ----
__global__ __launch_bounds__(256) void attn_chunk(const float* __restrict__ qfull,
    const float* __restrict__ kv, const int* __restrict__ topk,
    float* __restrict__ om, float* __restrict__ ol, float* __restrict__ op) {
  __shared__ __align__(16) short krows[2][KRSZ_];     // 2 x 19,008 B
  __shared__ __align__(16) short P_lds[H_*VTS_];      // 1,536 B
  __shared__ float Spart[2*16*33];                    // 4,224 B
  __shared__ float fl[H_];
  __shared__ int tk_lds[CHUNK_];
  const int lin = blockIdx.x + 8*blockIdx.y;   // [0,512)
  const int xcd = lin & 7, ixc = lin >> 3;
  const int b  = xcd*8 + (ixc & 7);            // same-b blocks share an XCD slot
  const int kc = ixc >> 3;
  const int t = threadIdx.x;
  const int lane = t & 63, wid = t >> 6;
  const int wm = wid >> 1, dn = wid & 1;   // score role: head-block, d-half
  const int lk = lane & 15, lg = lane >> 4;
  const int l31 = lane & 31, hi = lane >> 5;
  const int h16 = wm*16 + lk;

  bf16x8 qf[9];
  {
    const float* qb = &qfull[((size_t)b*H_ + h16)*DKV_ + dn*288 + lg*8];
    #pragma unroll
    for (int ks=0; ks<9; ++ks) {
      float4 u = ld4(qb + ks*32);
      float4 v = ld4(qb + ks*32 + 4);
      bf16x8 f;
      f[0]=f2b(u.x); f[1]=f2b(u.y); f[2]=f2b(u.z); f[3]=f2b(u.w);
      f[4]=f2b(v.x); f[5]=f2b(v.y); f[6]=f2b(v.z); f[7]=f2b(v.w);
      qf[ks] = f;
    }
  }

  int row_l[9], coff_l[9], woff_l[9];
  #pragma unroll
  for (int l=0;l<9;l++) {
    int idx = t + l*256;                 // 16*144 = 2304 = 9*256
    int row = idx/144, c = idx - row*144;
    int d0 = c*4;
    row_l[l] = row; coff_l[l] = d0;
    woff_l[l] = (d0>>4)*DGSTR_ + row*16 + (d0&15);
  }
  const float* kvb = kv + (size_t)b*S_*DKV_;
  const int kbase = b*TOPK_ + kc*CHUNK_;
  tk_lds[t] = topk[kbase + t];
  __syncthreads();

  float4 stA[9], stB[9];
  #define ISSUE(ST, G) { \
    _Pragma("unroll") \
    for (int l=0;l<9;l++) { \
      int ki = tk_lds[(G)*TILE_ + row_l[l]]; \
      ST[l] = ld4(kvb + (size_t)ki*DKV_ + coff_l[l]); \
    } }
  #define WBUF(KB, ST) { \
    _Pragma("unroll") \
    for (int l=0;l<9;l++) { \
      short4 s4; s4.x=f2b(ST[l].x); s4.y=f2b(ST[l].y); s4.z=f2b(ST[l].z); s4.w=f2b(ST[l].w); \
      *reinterpret_cast<short4*>(&(KB)[woff_l[l]]) = s4; \
    } }

  ISSUE(stA, 0);
  WBUF(krows[0], stA);
  ISSUE(stA, 1);
  ISSUE(stB, 2);
  asm volatile("s_waitcnt lgkmcnt(0)\n\ts_barrier" ::: "memory");

  float m_run = -INFINITY, l_run = 0.f;
  f32x16 acc[4];
  #pragma unroll
  for (int tt=0;tt<4;tt++)
    #pragma unroll
    for (int i=0;i<16;i++) acc[tt][i] = 0.f;

  const int soff = (dn*18 + (lg>>1))*DGSTR_ + lk*16 + (lg&1)*8;
  const int i15 = lk;
  const unsigned trc = (unsigned)((((wid*8) + ((lane>>4)&1))*DGSTR_ + (hi*8 + (i15>>2))*16 + (i15&3)*4)*2);

  #define PVBLOCK(KBP) { \
    float fsc = fl[l31]; \
    bf16x8 pf = *reinterpret_cast<const bf16x8*>(&P_lds[l31*VTS_ + hi*8]); \
    unsigned kaddr = (unsigned)(unsigned long long)(void*)(KBP); \
    s16x4 tr0_0 = tr_read(kaddr + trc + 0*1056); \
    s16x4 tr1_0 = tr_read(kaddr + trc + 0*1056 + 128); \
    s16x4 tr0_1 = tr_read(kaddr + trc + 1*1056); \
    s16x4 tr1_1 = tr_read(kaddr + trc + 1*1056 + 128); \
    s16x4 tr0_2 = tr_read(kaddr + trc + 2*1056); \
    s16x4 tr1_2 = tr_read(kaddr + trc + 2*1056 + 128); \
    s16x4 tr0_3 = tr_read(kaddr + trc + 3*1056); \
    s16x4 tr1_3 = tr_read(kaddr + trc + 3*1056 + 128); \
    _Pragma("unroll") \
    for (int tt=0;tt<4;tt++) \
      _Pragma("unroll") \
      for (int i=0;i<16;i++) acc[tt][i] *= fsc; \
    asm volatile("s_waitcnt lgkmcnt(0)" ::: "memory"); \
    __builtin_amdgcn_sched_barrier(0); \
    bf16x8 vf; \
    vf[0]=tr0_0[0]; vf[1]=tr0_0[1]; vf[2]=tr0_0[2]; vf[3]=tr0_0[3]; \
    vf[4]=tr1_0[0]; vf[5]=tr1_0[1]; vf[6]=tr1_0[2]; vf[7]=tr1_0[3]; \
    acc[0] = __builtin_amdgcn_mfma_f32_32x32x16_bf16(vf, pf, acc[0], 0, 0, 0); \
    vf[0]=tr0_1[0]; vf[1]=tr0_1[1]; vf[2]=tr0_1[2]; vf[3]=tr0_1[3]; \
    vf[4]=tr1_1[0]; vf[5]=tr1_1[1]; vf[6]=tr1_1[2]; vf[7]=tr1_1[3]; \
    acc[1] = __builtin_amdgcn_mfma_f32_32x32x16_bf16(vf, pf, acc[1], 0, 0, 0); \
    vf[0]=tr0_2[0]; vf[1]=tr0_2[1]; vf[2]=tr0_2[2]; vf[3]=tr0_2[3]; \
    vf[4]=tr1_2[0]; vf[5]=tr1_2[1]; vf[6]=tr1_2[2]; vf[7]=tr1_2[3]; \
    acc[2] = __builtin_amdgcn_mfma_f32_32x32x16_bf16(vf, pf, acc[2], 0, 0, 0); \
    vf[0]=tr0_3[0]; vf[1]=tr0_3[1]; vf[2]=tr0_3[2]; vf[3]=tr0_3[3]; \
    vf[4]=tr1_3[0]; vf[5]=tr1_3[1]; vf[6]=tr1_3[2]; vf[7]=tr1_3[3]; \
    acc[3] = __builtin_amdgcn_mfma_f32_32x32x16_bf16(vf, pf, acc[3], 0, 0, 0); \
  }

  for (int g=0; g<NG_; ++g) {
    const int cur = g & 1;
    short* kb  = krows[cur];
    short* kbp = krows[cur^1];   // tile g-1 (valid for g>=1)

    // ---- phase A': scores(g) + (g>0) PV(g-1) ----
    f32x4 sacc = {0.f,0.f,0.f,0.f};
    #pragma unroll
    for (int ks=0; ks<9; ++ks) {
      bf16x8 af = *reinterpret_cast<const bf16x8*>(&kb[soff + ks*(2*DGSTR_)]);
      sacc = __builtin_amdgcn_mfma_f32_16x16x32_bf16(af, qf[ks], sacc, 0, 0, 0);
    }
    if (g) PVBLOCK(kbp);
    #pragma unroll
    for (int r=0;r<4;r++)
      Spart[dn*528 + (lg*4+r)*33 + h16] = sacc[r];
    asm volatile("s_waitcnt lgkmcnt(0)\n\ts_barrier" ::: "memory");

    // ---- phase B: softmax + P/fl write + staged LDS write (tile g+1) + issue (tile g+3) ----
    float sfull[4];
    #pragma unroll
    for (int r=0;r<4;r++)
      sfull[r] = Spart[(lg*4+r)*33 + h16] + Spart[528 + (lg*4+r)*33 + h16];
    float tmax = fmaxf(fmaxf(sfull[0],sfull[1]), fmaxf(sfull[2],sfull[3]));
    tmax = fmaxf(tmax, __shfl_xor(tmax, 16));
    tmax = fmaxf(tmax, __shfl_xor(tmax, 32));
    float m_new = fmaxf(m_run, tmax);
    float fscale = __expf(m_run - m_new);
    m_run = m_new;
    float p0 = __expf(sfull[0]-m_new), p1 = __expf(sfull[1]-m_new);
    float p2 = __expf(sfull[2]-m_new), p3 = __expf(sfull[3]-m_new);
    float ps = (p0+p1)+(p2+p3);
    ps += __shfl_xor(ps, 16);
    ps += __shfl_xor(ps, 32);
    l_run = l_run*fscale + ps;
    if (dn==0) {
      short4 pk; pk.x=f2b(p0); pk.y=f2b(p1); pk.z=f2b(p2); pk.w=f2b(p3);
      *reinterpret_cast<short4*>(&P_lds[h16*VTS_ + lg*4]) = pk;
      if (lg==0) fl[h16] = fscale;
    }
    if ((g & 1) == 0) {
      if (g < NG_-1) WBUF(krows[cur^1], stA);
      if (g+3 < NG_) ISSUE(stA, g+3);
    } else {
      if (g < NG_-1) WBUF(krows[cur^1], stB);
      if (g+3 < NG_) ISSUE(stB, g+3);
    }
    asm volatile("s_waitcnt lgkmcnt(0)\n\ts_barrier" ::: "memory");
  }

  // epilogue: PV for tile NG-1 (krows[(NG_-1)&1], P_lds/fl from last B)
  PVBLOCK(krows[(NG_-1)&1]);

  if (dn==0 && lg==0) {
    om[(b*ACH_+kc)*H_ + h16] = m_run;
    ol[(b*ACH_+kc)*H_ + h16] = l_run;
  }
  #pragma unroll
  for (int tt=0;tt<4;tt++)
    #pragma unroll
    for (int q=0;q<4;q++) {
      float4 v = make_float4(acc[tt][4*q+0], acc[tt][4*q+1], acc[tt][4*q+2], acc[tt][4*q+3]);
      int r0 = wid*128 + tt*32 + 8*q + 4*hi;
      *reinterpret_cast<float4*>(&op[(((size_t)(b*ACH_+kc))*H_ + l31)*R_ + r0]) = v;
    }
  #undef ISSUE
  #undef WBUF
  #undef PVBLOCK
}

// ---------------- merge chunk partials ----------------
__global__ __launch_bounds__(128) void attn_merge(const float* __restrict__ om,
    const float* __restrict__ ol, const float* __restrict__ op, float* __restrict__ obuf) {
  const int bh = blockIdx.x;
  const int b = bh >> 5, h = bh & 31;
  const int t = threadIdx.x;
  float mv[8], lv[8], w[8];
  float M = -INFINITY;
  #pragma unroll
  for (int c=0;c<8;c++) { mv[c] = om[(b*ACH_+c)*H_ + h]; lv[c] = ol[(b*ACH_+c)*H_+h]; M = fmaxf(M, mv[c]); }
  float L = 0.f;
  #pragma unroll
  for (int c=0;c<8;c++) { w[c] = __expf(mv[c]-M); L += lv[c]*w[c]; }
  float inv = 1.0f / L;
  float4 s = make_float4(0.f,0.f,0.f,0.f);
  #pragma unroll
  for (int c=0;c<8;c++) {
    float4 v = ld4(&op[(((size_t)(b*ACH_+c))*H_ + h)*R_ + t*4]);
    s.x += v.x*w[c]; s.y += v.y*w[c]; s.z += v.z*w[c]; s.w += v.w*w[c];
  }
  s.x*=inv; s.y*=inv; s.z*=inv; s.w*=inv;
  *reinterpret_cast<float4*>(&obuf[((size_t)b*H_+h)*R_ + t*4]) = s;
}

// ---------------- final reduce of Wo partials ----------------
__global__ __launch_bounds__(256) void reduce_out(const float* __restrict__ op2, float* __restrict__ out) {
  int idx = blockIdx.x*256 + threadIdx.x; // float4 index
  float4 s = make_float4(0.f,0.f,0.f,0.f);
  #pragma unroll
  for (int c=0;c<KCH_;c++) {
    float4 v = ld4(&op2[(size_t)c*B_*HID_ + (size_t)idx*4]);
    s.x+=v.x; s.y+=v.y; s.z+=v.z; s.w+=v.w;
  }
  *reinterpret_cast<float4*>(&out[(size_t)idx*4]) = s;
}

extern "C" void kernel_launch(void* const* d_in, const int* in_sizes, int n_in,
                              void* d_out, int out_size, void* d_ws, size_t ws_size,
                              hipStream_t stream) {
  (void)in_sizes; (void)n_in; (void)out_size; (void)ws_size;
  const float* x   = (const float*)d_in[0];
  const float* Wq  = (const float*)d_in[1];
  const float* WK  = (const float*)d_in[2];
  const float* WKs = (const float*)d_in[3];
  const float* WV  = (const float*)d_in[4];
  const float* WVs = (const float*)d_in[5];
  const float* Wo  = (const float*)d_in[6];
  const float* kv  = (const float*)d_in[7];
  const int* topk  = (const int*)d_in[8];
  const int* pos   = (const int*)d_in[9];
  float* ws = (float*)d_ws;
  float* qp    = ws;                                   // 16*64*6144   = 6,291,456
  float* qn    = qp    + (size_t)KCH_*64*6144;         // 64*32*128    =   262,144
  float* qfull = qn    + (size_t)64*32*128;            // 64*32*576    = 1,179,648
  float* om    = qfull + (size_t)64*32*576;            // 64*8*32
  float* ol    = om    + (size_t)64*8*32;              // 64*8*32
  float* op    = ol    + (size_t)64*8*32;              // 64*8*32*512  = 8,388,608
  float* obuf  = op    + (size_t)64*8*32*512;          // 64*32*512    = 1,048,576
  float* midp  = obuf  + (size_t)64*32*512;            // 2*64*4096    =   524,288
  float* op2   = midp  + (size_t)2*64*4096;            // 16*64*4096   = 4,194,304
  float* outf  = (float*)d_out;
  const float SC = 0.0721687836487032f; // 1/sqrt(192)

  gemm64_mfma<<<dim3(48,KCH_),256,0,stream>>>(x, nullptr, Wq, qp, NQ_, HID_);
  reduce_rope<<<64,256,0,stream>>>(qp, pos, qn, qfull);
  // ql = q_nope @ W_K[h]^T * (WKs*SC) -> qfull[:, :, 0:512]
  gemm64x64_mfma<<<dim3(32,8,1),256,0,stream>>>(qn, NOPE_, WK, NOPE_, R_*NOPE_,
      WKs, SC, qfull, H_*DKV_, DKV_, 0, 1);
  attn_chunk<<<dim3(8,64),256,0,stream>>>(qfull, kv, topk, om, ol, op);
  attn_merge<<<2048,128,0,stream>>>(om, ol, op, obuf);
  // vproj partials: mid_p[kc] = o @ W_V[h]^T * WVs over K-half kc
  gemm64x64_mfma<<<dim3(32,2,2),256,0,stream>>>(obuf, R_, WV, R_, V_*R_,
      WVs, 1.0f, midp, HID_, V_, B_*HID_, 2);
  // out partials: (mid_p0 + mid_p1) @ Wo
  gemm64_mfma<<<dim3(32,KCH_),256,0,stream>>>(midp, midp + (size_t)B_*HID_, Wo, op2, HID_, HID_);
  reduce_out<<<256,256,0,stream>>>(op2, outf);
}